// Round 14
// baseline (1296.844 us; speedup 1.0000x reference)
//
#include <hip/hip_runtime.h>
#include <hip/hip_bf16.h>

// ---------------------------------------------------------------------------
// VQ-VAE forward, fp32. NCHW.
// R14 = R13 (best: 1295us) + residual-block fusion: res_fused = 3x3 stage
// (exact conv_gemm CPB=32 path) -> h in LDS [32][256] (union, 32KB) -> 1x1
// K=32 stage with relu-at-load + resid add. Removes 4 dispatches + 4 C
// round-trips. In-place halo hazard avoided via A ping-pong:
// er1 Bb->A, er2 A->Bb, dr1 D->A, dr2 A->D.
// Per-output FMA chains bit-identical to R13 everywhere (stage1: ci asc, kk
// asc; stage2: k asc; bias/resid in epilogue) — R3 lesson: VQ argmin flips
// on 1-ulp upstream changes.
// conv_gemm / convt_gemm2 / convt2_quad / vq_gemm / repack_all: unchanged.
// ---------------------------------------------------------------------------

__device__ __forceinline__ float rp_elem(const float* __restrict__ src,
                                         int i, int COUT, int CIN, int KK)
{
    const int co = i % COUT;
    const int t  = i / COUT;
    const int kk = t % KK;
    const int ci = t / KK;
    return src[(co * CIN + ci) * KK + kk];
}

// One kernel repacks all weights + codebook-transpose into WR.
__global__ __launch_bounds__(256) void repack_all(
    const float* __restrict__ e1,  const float* __restrict__ e2,
    const float* __restrict__ er1a, const float* __restrict__ er1b,
    const float* __restrict__ er2a, const float* __restrict__ er2b,
    const float* __restrict__ pre, const float* __restrict__ d1,
    const float* __restrict__ dr1a, const float* __restrict__ dr1b,
    const float* __restrict__ dr2a, const float* __restrict__ dr2b,
    const float* __restrict__ t1, const float* __restrict__ cb,
    float* __restrict__ WR)
{
    const int idx = blockIdx.x * 256 + threadIdx.x;
    if (idx >= 221696) return;
    float v;
    if      (idx < 512)    v = rp_elem(e1,   idx,          32,  1, 16);
    else if (idx < 33280)  v = rp_elem(e2,   idx - 512,    64, 32, 16);
    else if (idx < 51712)  v = rp_elem(er1a, idx - 33280,  32, 64,  9);
    else if (idx < 53760)  v = rp_elem(er1b, idx - 51712,  64, 32,  1);
    else if (idx < 72192)  v = rp_elem(er2a, idx - 53760,  32, 64,  9);
    else if (idx < 74240)  v = rp_elem(er2b, idx - 72192,  64, 32,  1);
    else if (idx < 78336)  v = rp_elem(pre,  idx - 74240,  64, 64,  1);
    else if (idx < 115200) v = rp_elem(d1,   idx - 78336,  64, 64,  9);
    else if (idx < 133632) v = rp_elem(dr1a, idx - 115200, 32, 64,  9);
    else if (idx < 135680) v = rp_elem(dr1b, idx - 133632, 64, 32,  1);
    else if (idx < 154112) v = rp_elem(dr2a, idx - 135680, 32, 64,  9);
    else if (idx < 156160) v = rp_elem(dr2b, idx - 154112, 64, 32,  1);
    else if (idx < 188928) {
        // t1: [pr][k2=ci*2+ta][q=pc*2+tb][co]
        const int i  = idx - 156160;
        const int co = i & 31;
        const int q  = (i >> 5) & 3;
        const int k2 = (i >> 7) & 127;
        const int pr = i >> 14;
        const int pc = q >> 1, tb = q & 1;
        const int ci = k2 >> 1, ta = k2 & 1;
        const int kh = (1 - pr) + 2 * ta, kw = (1 - pc) + 2 * tb;
        v = t1[((ci * 32 + co) * 4 + kh) * 4 + kw];
    } else {
        const int i = idx - 188928;           // cbT: [dim][code]
        const int code = i & 511;
        const int dim  = i >> 9;
        v = cb[code * 64 + dim];
    }
    WR[idx] = v;
}

// ee[k] = sum_i cb[k][i]^2, exact ascending fmaf chain (matches reference).
__global__ __launch_bounds__(256) void vq_prep_ee(
    const float* __restrict__ cb, float* __restrict__ ee)
{
    const int k = blockIdx.x * 256 + threadIdx.x;  // grid(2) -> k < 512
    const float* __restrict__ cp = cb + (size_t)k * 64;
    float s = 0.0f;
#pragma unroll
    for (int i = 0; i < 64; i++) s = fmaf(cp[i], cp[i], s);
    ee[k] = s;
}

// GEMM-form conv (validated R13). Block: CPB couts x 256 pixels; thread:
// CPTHD x 4 pixels. K-chunks double-buffered in LDS; K=4 tap-split.
template<int CTOT, int CPB, int CIN, int K, int S, int PAD,
         bool RELU_IN, bool HAS_BIAS, bool RESID, bool RELU_OUT>
__global__ __launch_bounds__(256) void conv_gemm(
    const float* __restrict__ in, const float* __restrict__ wr,
    const float* __restrict__ bias, const float* __restrict__ resid,
    float* __restrict__ out,
    int H, int W, int OH, int OW)
{
    constexpr int KK  = K * K;
    constexpr int CIC = (K == 1) ? 8 : 1;
    constexpr int TS  = (K == 4) ? 2 : 1;
    constexpr int KC  = CIC * KK / TS;
    constexpr int NCH = (CIN * TS) / CIC;
    constexpr int NT  = 256;
    constexpr int CPTHD = CPB / 4;
    __shared__ __align__(16) float As[2][KC * NT];

    const int tid = threadIdx.x;
    const int tpx = tid & 63;
    const int tco = __builtin_amdgcn_readfirstlane(tid >> 6);
    const int co0 = blockIdx.y * CPB + tco * CPTHD;

    const int ohow = OH * OW;
    const int n_st = blockIdx.x * NT + tid;
    const int b_st = n_st / ohow;
    const int hw_s = n_st % ohow;
    const int ih0 = (hw_s / OW) * S - PAD;
    const int iw0 = (hw_s % OW) * S - PAD;
    const float* __restrict__ inb = in + (size_t)b_st * CIN * H * W;

    float acc[CPTHD][4];
#pragma unroll
    for (int c = 0; c < CPTHD; c++) {
        const float bz = HAS_BIAS ? bias[co0 + c] : 0.0f;
#pragma unroll
        for (int q = 0; q < 4; q++) acc[c][q] = bz;
    }

    float pf[KC];
    auto stage_load = [&](int ch) {
#pragma unroll
        for (int t = 0; t < KC; t++) {
            int ci, kh, kw;
            if constexpr (K == 1) {
                ci = ch * 8 + t; kh = 0; kw = 0;
            } else if constexpr (K == 3) {
                ci = ch; kh = t / 3; kw = t % 3;
            } else {                                 // K == 4, TS = 2
                ci = ch >> 1;
                const int kk = ((ch & 1) << 3) + t;
                kh = kk >> 2; kw = kk & 3;
            }
            const int ih = ih0 + kh, iw = iw0 + kw;
            float v = 0.0f;
            if (ih >= 0 && ih < H && iw >= 0 && iw < W)
                v = inb[(size_t)ci * H * W + ih * W + iw];
            if (RELU_IN) v = fmaxf(v, 0.0f);
            pf[t] = v;
        }
    };

    stage_load(0);
#pragma unroll
    for (int t = 0; t < KC; t++) As[0][t * NT + tid] = pf[t];
    __syncthreads();

#pragma unroll 2
    for (int c = 0; c < NCH; c++) {
        const int cur = c & 1;
        if (c + 1 < NCH) stage_load(c + 1);

#pragma unroll
        for (int t = 0; t < KC; t++) {
            const float4 a4 = *(const float4*)(As[cur] + t * NT + tpx * 4);
            const float* __restrict__ wk =
                wr + (size_t)(c * KC + t) * CTOT + co0;
#pragma unroll
            for (int cc = 0; cc < CPTHD; cc++) {
                const float w = wk[cc];
                acc[cc][0] = fmaf(a4.x, w, acc[cc][0]);
                acc[cc][1] = fmaf(a4.y, w, acc[cc][1]);
                acc[cc][2] = fmaf(a4.z, w, acc[cc][2]);
                acc[cc][3] = fmaf(a4.w, w, acc[cc][3]);
            }
        }

        if (c + 1 < NCH) {
#pragma unroll
            for (int t = 0; t < KC; t++) As[1 - cur][t * NT + tid] = pf[t];
        }
        __syncthreads();
    }

    const int n_c  = blockIdx.x * NT + tpx * 4;
    const int b_c  = n_c / ohow;
    const int hw_c = n_c % ohow;
    float* __restrict__ op = out + (size_t)b_c * CTOT * ohow + hw_c;
    const float* __restrict__ rp =
        RESID ? (resid + (size_t)b_c * CTOT * ohow + hw_c) : nullptr;
#pragma unroll
    for (int c = 0; c < CPTHD; c++) {
        const size_t off = (size_t)(co0 + c) * ohow;
        float4 r = make_float4(acc[c][0], acc[c][1], acc[c][2], acc[c][3]);
        if (RESID) {
            const float4 rv = *(const float4*)(rp + off);
            r.x += rv.x; r.y += rv.y; r.z += rv.z; r.w += rv.w;
        }
        if (RELU_OUT) {
            r.x = fmaxf(r.x, 0.f); r.y = fmaxf(r.y, 0.f);
            r.z = fmaxf(r.z, 0.f); r.w = fmaxf(r.w, 0.f);
        }
        *(float4*)(op + off) = r;
    }
}

// Fused residual block: out = in + W2 . relu( W1 *3x3* relu(in) ).
// H=W=64, CIN=64, CMID=32, COUT=64. Block = 256 px, grid = 512.
// Stage 1: exact conv_gemm<32,32,64,3,...,RELU_IN> math (ci asc, kk asc).
// h parked in LDS [32][256] (union with stage-1 buffer). Stage 2: 1x1
// K=32, relu applied at LDS load (== unfused RELU_IN staging), resid in
// epilogue. Both chains bit-identical to the unfused pair.
__global__ __launch_bounds__(256) void res_fused(
    const float* __restrict__ in, const float* __restrict__ wr1,
    const float* __restrict__ wr2, float* __restrict__ out)
{
    constexpr int NT = 256;
    __shared__ __align__(16) float S[8192];           // 32 KB union
    float* As1 = S;                                    // [2][9*256] = 4608

    const int tid = threadIdx.x;
    const int tpx = tid & 63;
    const int tco = __builtin_amdgcn_readfirstlane(tid >> 6);

    const int n_st = blockIdx.x * NT + tid;
    const int b = n_st >> 12;
    const int hw_s = n_st & 4095;
    const int ih0 = (hw_s >> 6) - 1;
    const int iw0 = (hw_s & 63) - 1;
    const float* __restrict__ inb = in + (size_t)b * 64 * 4096;

    // ---- stage 1: 3x3, 64 -> 32, relu-in, no bias ----
    const int co1 = tco * 8;
    float acc1[8][4];
#pragma unroll
    for (int c = 0; c < 8; c++)
#pragma unroll
        for (int q = 0; q < 4; q++) acc1[c][q] = 0.0f;

    float pf[9];
    auto stage_load = [&](int ci) {
#pragma unroll
        for (int t = 0; t < 9; t++) {
            const int ih = ih0 + t / 3, iw = iw0 + t % 3;
            float v = 0.0f;
            if (ih >= 0 && ih < 64 && iw >= 0 && iw < 64)
                v = inb[(size_t)ci * 4096 + ih * 64 + iw];
            pf[t] = fmaxf(v, 0.0f);
        }
    };

    stage_load(0);
#pragma unroll
    for (int t = 0; t < 9; t++) As1[t * NT + tid] = pf[t];
    __syncthreads();

#pragma unroll 2
    for (int c = 0; c < 64; c++) {
        const int cur = c & 1;
        if (c + 1 < 64) stage_load(c + 1);

#pragma unroll
        for (int t = 0; t < 9; t++) {
            const float4 a4 =
                *(const float4*)(As1 + (cur * 9 + t) * NT + tpx * 4);
            const float* __restrict__ wk = wr1 + (size_t)(c * 9 + t) * 32 + co1;
#pragma unroll
            for (int cc = 0; cc < 8; cc++) {
                const float w = wk[cc];
                acc1[cc][0] = fmaf(a4.x, w, acc1[cc][0]);
                acc1[cc][1] = fmaf(a4.y, w, acc1[cc][1]);
                acc1[cc][2] = fmaf(a4.z, w, acc1[cc][2]);
                acc1[cc][3] = fmaf(a4.w, w, acc1[cc][3]);
            }
        }

        if (c + 1 < 64) {
#pragma unroll
            for (int t = 0; t < 9; t++) As1[((1 - cur) * 9 + t) * NT + tid] = pf[t];
        }
        __syncthreads();
    }

    // ---- park h in LDS [32][256] (reuses S; barrier above guarantees all
    // stage-1 reads done) ----
#pragma unroll
    for (int c = 0; c < 8; c++)
        *(float4*)(S + (co1 + c) * 256 + tpx * 4) =
            make_float4(acc1[c][0], acc1[c][1], acc1[c][2], acc1[c][3]);
    __syncthreads();

    // ---- stage 2: 1x1, 32 -> 64, relu at load, resid add ----
    const int co2 = tco * 16;
    float acc2[16][4];
#pragma unroll
    for (int c = 0; c < 16; c++)
#pragma unroll
        for (int q = 0; q < 4; q++) acc2[c][q] = 0.0f;

#pragma unroll 4
    for (int k = 0; k < 32; k++) {
        float4 a4 = *(const float4*)(S + k * 256 + tpx * 4);
        a4.x = fmaxf(a4.x, 0.f); a4.y = fmaxf(a4.y, 0.f);
        a4.z = fmaxf(a4.z, 0.f); a4.w = fmaxf(a4.w, 0.f);
        const float* __restrict__ wk = wr2 + (size_t)k * 64 + co2;
#pragma unroll
        for (int cc = 0; cc < 16; cc++) {
            const float w = wk[cc];
            acc2[cc][0] = fmaf(a4.x, w, acc2[cc][0]);
            acc2[cc][1] = fmaf(a4.y, w, acc2[cc][1]);
            acc2[cc][2] = fmaf(a4.z, w, acc2[cc][2]);
            acc2[cc][3] = fmaf(a4.w, w, acc2[cc][3]);
        }
    }

    const int n_c = blockIdx.x * NT + tpx * 4;
    const int hw_c = n_c & 4095;
    const float* __restrict__ rp = in + (size_t)b * 64 * 4096 + hw_c;
    float* __restrict__ op = out + (size_t)b * 64 * 4096 + hw_c;
#pragma unroll
    for (int c = 0; c < 16; c++) {
        const size_t off = (size_t)(co2 + c) * 4096;
        const float4 rv = *(const float4*)(rp + off);
        *(float4*)(op + off) = make_float4(
            acc2[c][0] + rv.x, acc2[c][1] + rv.y,
            acc2[c][2] + rv.z, acc2[c][3] + rv.w);
    }
}

// t1 pc-merged GEMM (validated R12).
__global__ __launch_bounds__(256) void convt_gemm2(
    const float* __restrict__ in, const float* __restrict__ wr,
    const float* __restrict__ bias, float* __restrict__ out)
{
    constexpr int NT = 256;
    __shared__ __align__(16) float As[4 * 3 * NT];

    const int tid = threadIdx.x;
    const int tpx = tid & 63;
    const int tco = __builtin_amdgcn_readfirstlane(tid >> 6);
    const int co0 = tco * 8;
    const int pr = blockIdx.y;

    const int n_st = blockIdx.x * NT + tid;
    const int b = n_st >> 12;
    const int i_st = (n_st & 4095) >> 6;
    const int j_st = n_st & 63;
    const float* __restrict__ inb = in + (size_t)b * 64 * 4096;

    float acc[8][4][2];
#pragma unroll
    for (int c = 0; c < 8; c++) {
        const float bz = bias[co0 + c];
#pragma unroll
        for (int p = 0; p < 4; p++) {
            acc[c][p][0] = bz;
            acc[c][p][1] = bz;
        }
    }

    const float* __restrict__ wpr = wr + (size_t)pr * 128 * 4 * 32;

#pragma unroll 1
    for (int ch = 0; ch < 32; ch++) {
        const int k20 = ch * 4;
        __syncthreads();
#pragma unroll
        for (int t = 0; t < 4; t++) {
            const int k2 = k20 + t;
            const int ci = k2 >> 1;
            const int ta = k2 & 1;
            const int ih = i_st + pr - ta;
            const bool rok = (ih >= 0) && (ih < 64);
            const float* __restrict__ row = inb + (size_t)ci * 4096 + ih * 64;
#pragma unroll
            for (int m = 0; m < 3; m++) {
                const int iw = j_st + m - 1;
                float v = 0.0f;
                if (rok && iw >= 0 && iw < 64) v = row[iw];
                As[(t * 3 + m) * NT + tid] = v;
            }
        }
        __syncthreads();

#pragma unroll
        for (int t = 0; t < 4; t++) {
            float4 a[3];
#pragma unroll
            for (int m = 0; m < 3; m++)
                a[m] = *(const float4*)(As + (t * 3 + m) * NT + tpx * 4);
            const float* __restrict__ wk = wpr + (size_t)(k20 + t) * 4 * 32 + co0;
#pragma unroll
            for (int tb = 0; tb < 2; tb++) {
#pragma unroll
                for (int pc = 0; pc < 2; pc++) {
                    const int q = pc * 2 + tb;
                    const int m = pc - tb + 1;
                    const float* __restrict__ wt = wk + q * 32;
                    const float vx = a[m].x, vy = a[m].y,
                                vz = a[m].z, vw = a[m].w;
#pragma unroll
                    for (int c = 0; c < 8; c++) {
                        const float w = wt[c];
                        acc[c][0][pc] = fmaf(vx, w, acc[c][0][pc]);
                        acc[c][1][pc] = fmaf(vy, w, acc[c][1][pc]);
                        acc[c][2][pc] = fmaf(vz, w, acc[c][2][pc]);
                        acc[c][3][pc] = fmaf(vw, w, acc[c][3][pc]);
                    }
                }
            }
        }
    }

    const int n_c = blockIdx.x * NT + tpx * 4;
    const int i_c = (n_c & 4095) >> 6;
    const int j_c = n_c & 63;
    const int oh = 2 * i_c + pr;
    float* __restrict__ ob =
        out + (size_t)b * 32 * 16384 + (size_t)oh * 128 + 2 * j_c;
#pragma unroll
    for (int c = 0; c < 8; c++) {
        float* __restrict__ o = ob + (size_t)(co0 + c) * 16384;
        const float4 v0 = make_float4(
            fmaxf(acc[c][0][0], 0.f), fmaxf(acc[c][0][1], 0.f),
            fmaxf(acc[c][1][0], 0.f), fmaxf(acc[c][1][1], 0.f));
        const float4 v1 = make_float4(
            fmaxf(acc[c][2][0], 0.f), fmaxf(acc[c][2][1], 0.f),
            fmaxf(acc[c][3][0], 0.f), fmaxf(acc[c][3][1], 0.f));
        *(float4*)o = v0;
        *(float4*)(o + 4) = v1;
    }
}

// Final transposed conv (32 -> 1). (validated)
__global__ __launch_bounds__(256) void convt2_quad(
    const float* __restrict__ in, const float* __restrict__ w,
    const float* __restrict__ bias, float* __restrict__ out, int B)
{
    const int IH = 128, IW = 128, CIN = 32, OW = 256;
    const int j = threadIdx.x & 127;
    const int i = (blockIdx.x << 1) + (threadIdx.x >> 7);
    const int b = blockIdx.y;

    const float* __restrict__ inb = in + (size_t)b * CIN * IH * IW;
    const float bz = bias[0];
    float a00 = bz, a01 = bz, a10 = bz, a11 = bz;

    const bool okm = (i > 0);
    const bool okp = (i < IH - 1);
    const bool olm = (j > 0);
    const bool olp = (j < IW - 1);

#pragma unroll 4
    for (int ci = 0; ci < CIN; ci++) {
        const float* __restrict__ p = inb + ((size_t)ci * IH + i) * IW + j;
        const float* __restrict__ wp = w + ci * 16;
        const float vmm = (okm && olm) ? p[-IW - 1] : 0.f;
        const float vm0 = okm ? p[-IW] : 0.f;
        const float vmp = (okm && olp) ? p[-IW + 1] : 0.f;
        const float v0m = olm ? p[-1] : 0.f;
        const float v00 = p[0];
        const float v0p = olp ? p[1] : 0.f;
        const float vpm = (okp && olm) ? p[IW - 1] : 0.f;
        const float vp0 = okp ? p[IW] : 0.f;
        const float vpp = (okp && olp) ? p[IW + 1] : 0.f;
        a00 = fmaf(v00, wp[1 * 4 + 1], a00);
        a00 = fmaf(v0m, wp[1 * 4 + 3], a00);
        a00 = fmaf(vm0, wp[3 * 4 + 1], a00);
        a00 = fmaf(vmm, wp[3 * 4 + 3], a00);
        a01 = fmaf(v0p, wp[1 * 4 + 0], a01);
        a01 = fmaf(v00, wp[1 * 4 + 2], a01);
        a01 = fmaf(vmp, wp[3 * 4 + 0], a01);
        a01 = fmaf(vm0, wp[3 * 4 + 2], a01);
        a10 = fmaf(vp0, wp[0 * 4 + 1], a10);
        a10 = fmaf(vpm, wp[0 * 4 + 3], a10);
        a10 = fmaf(v00, wp[2 * 4 + 1], a10);
        a10 = fmaf(v0m, wp[2 * 4 + 3], a10);
        a11 = fmaf(vpp, wp[0 * 4 + 0], a11);
        a11 = fmaf(vp0, wp[0 * 4 + 2], a11);
        a11 = fmaf(v0p, wp[2 * 4 + 0], a11);
        a11 = fmaf(v00, wp[2 * 4 + 2], a11);
    }

    float* __restrict__ outb = out + (size_t)b * 256 * 256;
    ((float2*)(outb + (size_t)(2 * i) * OW))[j] = make_float2(a00, a01);
    ((float2*)(outb + (size_t)(2 * i + 1) * OW))[j] = make_float2(a10, a11);
}

// VQ-GEMM (validated R9). DO NOT reorder any fmaf chain (R3).
__global__ __launch_bounds__(256) void vq_gemm(
    const float* __restrict__ h,    // (32,64,4096)
    const float* __restrict__ cb,   // (512,64) row-major (gather)
    const float* __restrict__ cbT,  // (64,512) dim-major (matmul)
    const float* __restrict__ ee,   // (512)
    float* __restrict__ q)          // (32,64,4096)
{
    __shared__ __align__(16) float As[64 * 128];
    __shared__ float xx_sh[128];
    __shared__ float pd[4 * 128];
    __shared__ int   pk[4 * 128];
    __shared__ int   bidx_sh[128];

    const int tid = threadIdx.x;
    const int tpx = tid & 63;
    const int w = __builtin_amdgcn_readfirstlane(tid >> 6);
    const int n0 = blockIdx.x * 128;
    const int b  = n0 >> 12;
    const int hw0 = n0 & 4095;

    const float* __restrict__ hb = h + (size_t)b * 64 * 4096 + hw0;
#pragma unroll
    for (int m = 0; m < 32; m++) {
        const int idx = m * 256 + tid;
        const int k = idx >> 7, p = idx & 127;
        As[idx] = hb[(size_t)k * 4096 + p];
    }
    __syncthreads();

    if (tid < 128) {
        float s = 0.0f;
#pragma unroll
        for (int i = 0; i < 64; i++) {
            const float v = As[i * 128 + tid];
            s = fmaf(v, v, s);
        }
        xx_sh[tid] = s;
    }
    __syncthreads();

    const float xx0 = xx_sh[tpx * 2];
    const float xx1 = xx_sh[tpx * 2 + 1];
    const int cwave = w * 128;

    float best0 = 3.402823466e+38f, best1 = 3.402823466e+38f;
    int bk0 = 0, bk1 = 0;

#pragma unroll 1
    for (int ch = 0; ch < 16; ch++) {
        const int cbase = cwave + ch * 8;
        float acc[8][2];
#pragma unroll
        for (int c = 0; c < 8; c++) { acc[c][0] = 0.0f; acc[c][1] = 0.0f; }

#pragma unroll 8
        for (int k = 0; k < 64; k++) {
            const float2 a2 = *(const float2*)(As + k * 128 + tpx * 2);
            const float* __restrict__ wk = cbT + (size_t)k * 512 + cbase;
#pragma unroll
            for (int c = 0; c < 8; c++) {
                const float wv = wk[c];
                acc[c][0] = fmaf(a2.x, wv, acc[c][0]);
                acc[c][1] = fmaf(a2.y, wv, acc[c][1]);
            }
        }
        const float* __restrict__ eep = ee + cbase;
#pragma unroll
        for (int c = 0; c < 8; c++) {
            const float eec = eep[c];
            const float d0 = xx0 - 2.0f * acc[c][0] + eec;
            const float d1 = xx1 - 2.0f * acc[c][1] + eec;
            if (d0 < best0) { best0 = d0; bk0 = cbase + c; }
            if (d1 < best1) { best1 = d1; bk1 = cbase + c; }
        }
    }

    pd[w * 128 + tpx * 2]     = best0;
    pd[w * 128 + tpx * 2 + 1] = best1;
    pk[w * 128 + tpx * 2]     = bk0;
    pk[w * 128 + tpx * 2 + 1] = bk1;
    __syncthreads();

    if (tid < 128) {
        float bd = pd[tid]; int bk = pk[tid];
#pragma unroll
        for (int ww = 1; ww < 4; ww++) {
            const float od = pd[ww * 128 + tid];
            if (od < bd) { bd = od; bk = pk[ww * 128 + tid]; }
        }
        bidx_sh[tid] = bk;
    }
    __syncthreads();

    {
        const int p  = tid & 127;
        const int d0 = (tid >> 7) * 32;
        const int bk = bidx_sh[p];
        const float4* __restrict__ cp4 = (const float4*)(cb + (size_t)bk * 64 + d0);
        float* __restrict__ qb = q + ((size_t)b * 64 + d0) * 4096 + hw0 + p;
#pragma unroll
        for (int i = 0; i < 8; i++) {
            const float4 v = cp4[i];
            qb[(size_t)(4 * i + 0) * 4096] = v.x;
            qb[(size_t)(4 * i + 1) * 4096] = v.y;
            qb[(size_t)(4 * i + 2) * 4096] = v.z;
            qb[(size_t)(4 * i + 3) * 4096] = v.w;
        }
    }
}

extern "C" void kernel_launch(void* const* d_in, const int* in_sizes, int n_in,
                              void* d_out, int out_size, void* d_ws, size_t ws_size,
                              hipStream_t stream) {
    const float* x      = (const float*)d_in[0];
    const float* w_e1   = (const float*)d_in[1];
    const float* b_e1   = (const float*)d_in[2];
    const float* w_e2   = (const float*)d_in[3];
    const float* b_e2   = (const float*)d_in[4];
    const float* w_er1a = (const float*)d_in[5];
    const float* w_er1b = (const float*)d_in[6];
    const float* w_er2a = (const float*)d_in[7];
    const float* w_er2b = (const float*)d_in[8];
    const float* w_pre  = (const float*)d_in[9];
    const float* b_pre  = (const float*)d_in[10];
    const float* cbk    = (const float*)d_in[11];
    const float* w_d1   = (const float*)d_in[12];
    const float* b_d1   = (const float*)d_in[13];
    const float* w_dr1a = (const float*)d_in[14];
    const float* w_dr1b = (const float*)d_in[15];
    const float* w_dr2a = (const float*)d_in[16];
    const float* w_dr2b = (const float*)d_in[17];
    const float* w_t1   = (const float*)d_in[18];
    const float* b_t1   = (const float*)d_in[19];
    const float* w_t2   = (const float*)d_in[20];
    const float* b_t2   = (const float*)d_in[21];
    float* out = (float*)d_out;

    float* A  = (float*)d_ws;            // 16777216 floats (scratch + t1 out)
    float* Bb = A  + 16777216;           // (32,64,64,64) = 8388608
    float* C  = Bb + 8388608;            // 4194304 (unused after fusion)
    float* D  = C  + 4194304;            // (32,64,64,64) = 8388608
    float* WR = D  + 8388608;            // repacked weights + cbT (221696)
    float* EE = WR + 221696;             // ee (512)

    float* r_e1  = WR;
    float* r_e2  = WR + 512;
    float* r_er1a = WR + 33280;
    float* r_er1b = WR + 51712;
    float* r_er2a = WR + 53760;
    float* r_er2b = WR + 72192;
    float* r_pre = WR + 74240;
    float* r_d1  = WR + 78336;
    float* r_dr1a = WR + 115200;
    float* r_dr1b = WR + 133632;
    float* r_dr2a = WR + 135680;
    float* r_dr2b = WR + 154112;
    float* r_t1  = WR + 156160;
    float* r_cbT = WR + 188928;

    const dim3 blk(256);

    repack_all<<<dim3(866), blk, 0, stream>>>(
        w_e1, w_e2, w_er1a, w_er1b, w_er2a, w_er2b, w_pre, w_d1,
        w_dr1a, w_dr1b, w_dr2a, w_dr2b, w_t1, cbk, WR);
    vq_prep_ee<<<dim3(2), blk, 0, stream>>>(cbk, EE);

    // Encoder
    conv_gemm<32, 32, 1, 4, 2, 1, false, true, false, true>
        <<<dim3(2048, 1), blk, 0, stream>>>(x, r_e1, b_e1, nullptr, A,
                                            256, 256, 128, 128);
    conv_gemm<64, 32, 32, 4, 2, 1, false, true, false, false>
        <<<dim3(512, 2), blk, 0, stream>>>(A, r_e2, b_e2, nullptr, Bb,
                                           128, 128, 64, 64);
    // er1: Bb -> A ; er2: A -> Bb (ping-pong avoids in-place halo race)
    res_fused<<<dim3(512), blk, 0, stream>>>(Bb, r_er1a, r_er1b, A);
    res_fused<<<dim3(512), blk, 0, stream>>>(A, r_er2a, r_er2b, Bb);
    conv_gemm<64, 32, 64, 1, 1, 0, false, true, false, false>
        <<<dim3(512, 2), blk, 0, stream>>>(Bb, r_pre, b_pre, nullptr, D,
                                           64, 64, 64, 64);
    // VQ
    vq_gemm<<<dim3(1024), blk, 0, stream>>>(D, cbk, r_cbT, EE, Bb);
    // Decoder
    conv_gemm<64, 16, 64, 3, 1, 1, false, true, false, false>
        <<<dim3(512, 4), blk, 0, stream>>>(Bb, r_d1, b_d1, nullptr, D,
                                           64, 64, 64, 64);
    // dr1: D -> A ; dr2: A -> D
    res_fused<<<dim3(512), blk, 0, stream>>>(D, r_dr1a, r_dr1b, A);
    res_fused<<<dim3(512), blk, 0, stream>>>(A, r_dr2a, r_dr2b, D);
    // t1 (pc-merged): grid (512 n-blocks, 2 pr-parities)
    convt_gemm2<<<dim3(512, 2), blk, 0, stream>>>(D, r_t1, b_t1, A);
    // t2
    convt2_quad<<<dim3(64, 32), blk, 0, stream>>>(A, w_t2, b_t2, out, 32);
}

// Round 15
// 1293.403 us; speedup vs baseline: 1.0027x; 1.0027x over previous
//
#include <hip/hip_runtime.h>
#include <hip/hip_bf16.h>

// ---------------------------------------------------------------------------
// VQ-VAE forward, fp32. NCHW.
// R15 = R14 + occupancy lever (R13's proven 2-0 win) on the 50%-capped
// kernels, numerics-identical:
//  (a) convt_gemm2: grid.y = 2pr x 2 cout-groups (1024->2048 blocks, 8/CU);
//      wave owns 4 couts (acc 32 VGPR); double-buffered staging, 1 barrier
//      per chunk. FMA chain per output: ci asc, ta asc, tb asc — unchanged.
//  (b) e2 / pre: CPB 32->16, grid.y 2->4 (d1's R13 win applied).
// R14 lesson: fusion was traffic-neutral because occupancy (not traffic)
// binds at this problem size (131k points).
// Per-output FMA chains bit-identical everywhere (R3 lesson: VQ argmin
// flips on 1-ulp upstream changes).
// ---------------------------------------------------------------------------

__device__ __forceinline__ float rp_elem(const float* __restrict__ src,
                                         int i, int COUT, int CIN, int KK)
{
    const int co = i % COUT;
    const int t  = i / COUT;
    const int kk = t % KK;
    const int ci = t / KK;
    return src[(co * CIN + ci) * KK + kk];
}

// One kernel repacks all weights + codebook-transpose into WR.
__global__ __launch_bounds__(256) void repack_all(
    const float* __restrict__ e1,  const float* __restrict__ e2,
    const float* __restrict__ er1a, const float* __restrict__ er1b,
    const float* __restrict__ er2a, const float* __restrict__ er2b,
    const float* __restrict__ pre, const float* __restrict__ d1,
    const float* __restrict__ dr1a, const float* __restrict__ dr1b,
    const float* __restrict__ dr2a, const float* __restrict__ dr2b,
    const float* __restrict__ t1, const float* __restrict__ cb,
    float* __restrict__ WR)
{
    const int idx = blockIdx.x * 256 + threadIdx.x;
    if (idx >= 221696) return;
    float v;
    if      (idx < 512)    v = rp_elem(e1,   idx,          32,  1, 16);
    else if (idx < 33280)  v = rp_elem(e2,   idx - 512,    64, 32, 16);
    else if (idx < 51712)  v = rp_elem(er1a, idx - 33280,  32, 64,  9);
    else if (idx < 53760)  v = rp_elem(er1b, idx - 51712,  64, 32,  1);
    else if (idx < 72192)  v = rp_elem(er2a, idx - 53760,  32, 64,  9);
    else if (idx < 74240)  v = rp_elem(er2b, idx - 72192,  64, 32,  1);
    else if (idx < 78336)  v = rp_elem(pre,  idx - 74240,  64, 64,  1);
    else if (idx < 115200) v = rp_elem(d1,   idx - 78336,  64, 64,  9);
    else if (idx < 133632) v = rp_elem(dr1a, idx - 115200, 32, 64,  9);
    else if (idx < 135680) v = rp_elem(dr1b, idx - 133632, 64, 32,  1);
    else if (idx < 154112) v = rp_elem(dr2a, idx - 135680, 32, 64,  9);
    else if (idx < 156160) v = rp_elem(dr2b, idx - 154112, 64, 32,  1);
    else if (idx < 188928) {
        // t1: [pr][k2=ci*2+ta][q=pc*2+tb][co]
        const int i  = idx - 156160;
        const int co = i & 31;
        const int q  = (i >> 5) & 3;
        const int k2 = (i >> 7) & 127;
        const int pr = i >> 14;
        const int pc = q >> 1, tb = q & 1;
        const int ci = k2 >> 1, ta = k2 & 1;
        const int kh = (1 - pr) + 2 * ta, kw = (1 - pc) + 2 * tb;
        v = t1[((ci * 32 + co) * 4 + kh) * 4 + kw];
    } else {
        const int i = idx - 188928;           // cbT: [dim][code]
        const int code = i & 511;
        const int dim  = i >> 9;
        v = cb[code * 64 + dim];
    }
    WR[idx] = v;
}

// ee[k] = sum_i cb[k][i]^2, exact ascending fmaf chain (matches reference).
__global__ __launch_bounds__(256) void vq_prep_ee(
    const float* __restrict__ cb, float* __restrict__ ee)
{
    const int k = blockIdx.x * 256 + threadIdx.x;  // grid(2) -> k < 512
    const float* __restrict__ cp = cb + (size_t)k * 64;
    float s = 0.0f;
#pragma unroll
    for (int i = 0; i < 64; i++) s = fmaf(cp[i], cp[i], s);
    ee[k] = s;
}

// GEMM-form conv (validated R13). Block: CPB couts x 256 pixels; thread:
// CPTHD x 4 pixels. K-chunks double-buffered in LDS; K=4 tap-split.
template<int CTOT, int CPB, int CIN, int K, int S, int PAD,
         bool RELU_IN, bool HAS_BIAS, bool RESID, bool RELU_OUT>
__global__ __launch_bounds__(256) void conv_gemm(
    const float* __restrict__ in, const float* __restrict__ wr,
    const float* __restrict__ bias, const float* __restrict__ resid,
    float* __restrict__ out,
    int H, int W, int OH, int OW)
{
    constexpr int KK  = K * K;
    constexpr int CIC = (K == 1) ? 8 : 1;
    constexpr int TS  = (K == 4) ? 2 : 1;
    constexpr int KC  = CIC * KK / TS;
    constexpr int NCH = (CIN * TS) / CIC;
    constexpr int NT  = 256;
    constexpr int CPTHD = CPB / 4;
    __shared__ __align__(16) float As[2][KC * NT];

    const int tid = threadIdx.x;
    const int tpx = tid & 63;
    const int tco = __builtin_amdgcn_readfirstlane(tid >> 6);
    const int co0 = blockIdx.y * CPB + tco * CPTHD;

    const int ohow = OH * OW;
    const int n_st = blockIdx.x * NT + tid;
    const int b_st = n_st / ohow;
    const int hw_s = n_st % ohow;
    const int ih0 = (hw_s / OW) * S - PAD;
    const int iw0 = (hw_s % OW) * S - PAD;
    const float* __restrict__ inb = in + (size_t)b_st * CIN * H * W;

    float acc[CPTHD][4];
#pragma unroll
    for (int c = 0; c < CPTHD; c++) {
        const float bz = HAS_BIAS ? bias[co0 + c] : 0.0f;
#pragma unroll
        for (int q = 0; q < 4; q++) acc[c][q] = bz;
    }

    float pf[KC];
    auto stage_load = [&](int ch) {
#pragma unroll
        for (int t = 0; t < KC; t++) {
            int ci, kh, kw;
            if constexpr (K == 1) {
                ci = ch * 8 + t; kh = 0; kw = 0;
            } else if constexpr (K == 3) {
                ci = ch; kh = t / 3; kw = t % 3;
            } else {                                 // K == 4, TS = 2
                ci = ch >> 1;
                const int kk = ((ch & 1) << 3) + t;
                kh = kk >> 2; kw = kk & 3;
            }
            const int ih = ih0 + kh, iw = iw0 + kw;
            float v = 0.0f;
            if (ih >= 0 && ih < H && iw >= 0 && iw < W)
                v = inb[(size_t)ci * H * W + ih * W + iw];
            if (RELU_IN) v = fmaxf(v, 0.0f);
            pf[t] = v;
        }
    };

    stage_load(0);
#pragma unroll
    for (int t = 0; t < KC; t++) As[0][t * NT + tid] = pf[t];
    __syncthreads();

#pragma unroll 2
    for (int c = 0; c < NCH; c++) {
        const int cur = c & 1;
        if (c + 1 < NCH) stage_load(c + 1);

#pragma unroll
        for (int t = 0; t < KC; t++) {
            const float4 a4 = *(const float4*)(As[cur] + t * NT + tpx * 4);
            const float* __restrict__ wk =
                wr + (size_t)(c * KC + t) * CTOT + co0;
#pragma unroll
            for (int cc = 0; cc < CPTHD; cc++) {
                const float w = wk[cc];
                acc[cc][0] = fmaf(a4.x, w, acc[cc][0]);
                acc[cc][1] = fmaf(a4.y, w, acc[cc][1]);
                acc[cc][2] = fmaf(a4.z, w, acc[cc][2]);
                acc[cc][3] = fmaf(a4.w, w, acc[cc][3]);
            }
        }

        if (c + 1 < NCH) {
#pragma unroll
            for (int t = 0; t < KC; t++) As[1 - cur][t * NT + tid] = pf[t];
        }
        __syncthreads();
    }

    const int n_c  = blockIdx.x * NT + tpx * 4;
    const int b_c  = n_c / ohow;
    const int hw_c = n_c % ohow;
    float* __restrict__ op = out + (size_t)b_c * CTOT * ohow + hw_c;
    const float* __restrict__ rp =
        RESID ? (resid + (size_t)b_c * CTOT * ohow + hw_c) : nullptr;
#pragma unroll
    for (int c = 0; c < CPTHD; c++) {
        const size_t off = (size_t)(co0 + c) * ohow;
        float4 r = make_float4(acc[c][0], acc[c][1], acc[c][2], acc[c][3]);
        if (RESID) {
            const float4 rv = *(const float4*)(rp + off);
            r.x += rv.x; r.y += rv.y; r.z += rv.z; r.w += rv.w;
        }
        if (RELU_OUT) {
            r.x = fmaxf(r.x, 0.f); r.y = fmaxf(r.y, 0.f);
            r.z = fmaxf(r.z, 0.f); r.w = fmaxf(r.w, 0.f);
        }
        *(float4*)(op + off) = r;
    }
}

// Fused residual block (validated R14): out = in + W2.relu(W1 *3x3* relu(in)).
__global__ __launch_bounds__(256) void res_fused(
    const float* __restrict__ in, const float* __restrict__ wr1,
    const float* __restrict__ wr2, float* __restrict__ out)
{
    constexpr int NT = 256;
    __shared__ __align__(16) float S[8192];           // 32 KB union
    float* As1 = S;

    const int tid = threadIdx.x;
    const int tpx = tid & 63;
    const int tco = __builtin_amdgcn_readfirstlane(tid >> 6);

    const int n_st = blockIdx.x * NT + tid;
    const int b = n_st >> 12;
    const int hw_s = n_st & 4095;
    const int ih0 = (hw_s >> 6) - 1;
    const int iw0 = (hw_s & 63) - 1;
    const float* __restrict__ inb = in + (size_t)b * 64 * 4096;

    const int co1 = tco * 8;
    float acc1[8][4];
#pragma unroll
    for (int c = 0; c < 8; c++)
#pragma unroll
        for (int q = 0; q < 4; q++) acc1[c][q] = 0.0f;

    float pf[9];
    auto stage_load = [&](int ci) {
#pragma unroll
        for (int t = 0; t < 9; t++) {
            const int ih = ih0 + t / 3, iw = iw0 + t % 3;
            float v = 0.0f;
            if (ih >= 0 && ih < 64 && iw >= 0 && iw < 64)
                v = inb[(size_t)ci * 4096 + ih * 64 + iw];
            pf[t] = fmaxf(v, 0.0f);
        }
    };

    stage_load(0);
#pragma unroll
    for (int t = 0; t < 9; t++) As1[t * NT + tid] = pf[t];
    __syncthreads();

#pragma unroll 2
    for (int c = 0; c < 64; c++) {
        const int cur = c & 1;
        if (c + 1 < 64) stage_load(c + 1);

#pragma unroll
        for (int t = 0; t < 9; t++) {
            const float4 a4 =
                *(const float4*)(As1 + (cur * 9 + t) * NT + tpx * 4);
            const float* __restrict__ wk = wr1 + (size_t)(c * 9 + t) * 32 + co1;
#pragma unroll
            for (int cc = 0; cc < 8; cc++) {
                const float w = wk[cc];
                acc1[cc][0] = fmaf(a4.x, w, acc1[cc][0]);
                acc1[cc][1] = fmaf(a4.y, w, acc1[cc][1]);
                acc1[cc][2] = fmaf(a4.z, w, acc1[cc][2]);
                acc1[cc][3] = fmaf(a4.w, w, acc1[cc][3]);
            }
        }

        if (c + 1 < 64) {
#pragma unroll
            for (int t = 0; t < 9; t++) As1[((1 - cur) * 9 + t) * NT + tid] = pf[t];
        }
        __syncthreads();
    }

#pragma unroll
    for (int c = 0; c < 8; c++)
        *(float4*)(S + (co1 + c) * 256 + tpx * 4) =
            make_float4(acc1[c][0], acc1[c][1], acc1[c][2], acc1[c][3]);
    __syncthreads();

    const int co2 = tco * 16;
    float acc2[16][4];
#pragma unroll
    for (int c = 0; c < 16; c++)
#pragma unroll
        for (int q = 0; q < 4; q++) acc2[c][q] = 0.0f;

#pragma unroll 4
    for (int k = 0; k < 32; k++) {
        float4 a4 = *(const float4*)(S + k * 256 + tpx * 4);
        a4.x = fmaxf(a4.x, 0.f); a4.y = fmaxf(a4.y, 0.f);
        a4.z = fmaxf(a4.z, 0.f); a4.w = fmaxf(a4.w, 0.f);
        const float* __restrict__ wk = wr2 + (size_t)k * 64 + co2;
#pragma unroll
        for (int cc = 0; cc < 16; cc++) {
            const float w = wk[cc];
            acc2[cc][0] = fmaf(a4.x, w, acc2[cc][0]);
            acc2[cc][1] = fmaf(a4.y, w, acc2[cc][1]);
            acc2[cc][2] = fmaf(a4.z, w, acc2[cc][2]);
            acc2[cc][3] = fmaf(a4.w, w, acc2[cc][3]);
        }
    }

    const int n_c = blockIdx.x * NT + tpx * 4;
    const int hw_c = n_c & 4095;
    const float* __restrict__ rp = in + (size_t)b * 64 * 4096 + hw_c;
    float* __restrict__ op = out + (size_t)b * 64 * 4096 + hw_c;
#pragma unroll
    for (int c = 0; c < 16; c++) {
        const size_t off = (size_t)(co2 + c) * 4096;
        const float4 rv = *(const float4*)(rp + off);
        *(float4*)(op + off) = make_float4(
            acc2[c][0] + rv.x, acc2[c][1] + rv.y,
            acc2[c][2] + rv.z, acc2[c][3] + rv.w);
    }
}

// t1 pc-merged GEMM, R15: cout-split (grid.y = 2pr x 2 cout-groups) +
// double-buffered staging (1 barrier/chunk). Wave owns 4 couts.
// FMA order per output: ci asc, ta asc, tb asc — identical to R12/R14.
__global__ __launch_bounds__(256) void convt_gemm2(
    const float* __restrict__ in, const float* __restrict__ wr,
    const float* __restrict__ bias, float* __restrict__ out)
{
    constexpr int NT = 256;
    __shared__ __align__(16) float As[2][12 * NT];   // 24 KB

    const int tid = threadIdx.x;
    const int tpx = tid & 63;
    const int tco = __builtin_amdgcn_readfirstlane(tid >> 6);
    const int pr = blockIdx.y & 1;
    const int cg = blockIdx.y >> 1;
    const int co0 = cg * 16 + tco * 4;

    const int n_st = blockIdx.x * NT + tid;
    const int b = n_st >> 12;
    const int i_st = (n_st & 4095) >> 6;
    const int j_st = n_st & 63;
    const float* __restrict__ inb = in + (size_t)b * 64 * 4096;

    float acc[4][4][2];
#pragma unroll
    for (int c = 0; c < 4; c++) {
        const float bz = bias[co0 + c];
#pragma unroll
        for (int p = 0; p < 4; p++) {
            acc[c][p][0] = bz;
            acc[c][p][1] = bz;
        }
    }

    const float* __restrict__ wpr = wr + (size_t)pr * 128 * 4 * 32;

    float pf[12];
    auto stage_load = [&](int ch) {
#pragma unroll
        for (int t = 0; t < 4; t++) {
            const int k2 = ch * 4 + t;
            const int ci = k2 >> 1;
            const int ta = k2 & 1;
            const int ih = i_st + pr - ta;
            const bool rok = (ih >= 0) && (ih < 64);
            const float* __restrict__ row = inb + (size_t)ci * 4096 + ih * 64;
#pragma unroll
            for (int m = 0; m < 3; m++) {
                const int iw = j_st + m - 1;
                float v = 0.0f;
                if (rok && iw >= 0 && iw < 64) v = row[iw];
                pf[t * 3 + m] = v;
            }
        }
    };

    stage_load(0);
#pragma unroll
    for (int t = 0; t < 12; t++) As[0][t * NT + tid] = pf[t];
    __syncthreads();

#pragma unroll 2
    for (int ch = 0; ch < 32; ch++) {
        const int cur = ch & 1;
        if (ch + 1 < 32) stage_load(ch + 1);

#pragma unroll
        for (int t = 0; t < 4; t++) {
            float4 a[3];
#pragma unroll
            for (int m = 0; m < 3; m++)
                a[m] = *(const float4*)(As[cur] + (t * 3 + m) * NT + tpx * 4);
            const float* __restrict__ wk =
                wpr + (size_t)(ch * 4 + t) * 4 * 32 + co0;
#pragma unroll
            for (int tb = 0; tb < 2; tb++) {
#pragma unroll
                for (int pc = 0; pc < 2; pc++) {
                    const int q = pc * 2 + tb;
                    const int m = pc - tb + 1;
                    const float* __restrict__ wt = wk + q * 32;
                    const float vx = a[m].x, vy = a[m].y,
                                vz = a[m].z, vw = a[m].w;
#pragma unroll
                    for (int c = 0; c < 4; c++) {
                        const float w = wt[c];
                        acc[c][0][pc] = fmaf(vx, w, acc[c][0][pc]);
                        acc[c][1][pc] = fmaf(vy, w, acc[c][1][pc]);
                        acc[c][2][pc] = fmaf(vz, w, acc[c][2][pc]);
                        acc[c][3][pc] = fmaf(vw, w, acc[c][3][pc]);
                    }
                }
            }
        }

        if (ch + 1 < 32) {
#pragma unroll
            for (int t = 0; t < 12; t++) As[1 - cur][t * NT + tid] = pf[t];
        }
        __syncthreads();
    }

    const int n_c = blockIdx.x * NT + tpx * 4;
    const int i_c = (n_c & 4095) >> 6;
    const int j_c = n_c & 63;
    const int oh = 2 * i_c + pr;
    float* __restrict__ ob =
        out + (size_t)b * 32 * 16384 + (size_t)oh * 128 + 2 * j_c;
#pragma unroll
    for (int c = 0; c < 4; c++) {
        float* __restrict__ o = ob + (size_t)(co0 + c) * 16384;
        const float4 v0 = make_float4(
            fmaxf(acc[c][0][0], 0.f), fmaxf(acc[c][0][1], 0.f),
            fmaxf(acc[c][1][0], 0.f), fmaxf(acc[c][1][1], 0.f));
        const float4 v1 = make_float4(
            fmaxf(acc[c][2][0], 0.f), fmaxf(acc[c][2][1], 0.f),
            fmaxf(acc[c][3][0], 0.f), fmaxf(acc[c][3][1], 0.f));
        *(float4*)o = v0;
        *(float4*)(o + 4) = v1;
    }
}

// Final transposed conv (32 -> 1). (validated)
__global__ __launch_bounds__(256) void convt2_quad(
    const float* __restrict__ in, const float* __restrict__ w,
    const float* __restrict__ bias, float* __restrict__ out, int B)
{
    const int IH = 128, IW = 128, CIN = 32, OW = 256;
    const int j = threadIdx.x & 127;
    const int i = (blockIdx.x << 1) + (threadIdx.x >> 7);
    const int b = blockIdx.y;

    const float* __restrict__ inb = in + (size_t)b * CIN * IH * IW;
    const float bz = bias[0];
    float a00 = bz, a01 = bz, a10 = bz, a11 = bz;

    const bool okm = (i > 0);
    const bool okp = (i < IH - 1);
    const bool olm = (j > 0);
    const bool olp = (j < IW - 1);

#pragma unroll 4
    for (int ci = 0; ci < CIN; ci++) {
        const float* __restrict__ p = inb + ((size_t)ci * IH + i) * IW + j;
        const float* __restrict__ wp = w + ci * 16;
        const float vmm = (okm && olm) ? p[-IW - 1] : 0.f;
        const float vm0 = okm ? p[-IW] : 0.f;
        const float vmp = (okm && olp) ? p[-IW + 1] : 0.f;
        const float v0m = olm ? p[-1] : 0.f;
        const float v00 = p[0];
        const float v0p = olp ? p[1] : 0.f;
        const float vpm = (okp && olm) ? p[IW - 1] : 0.f;
        const float vp0 = okp ? p[IW] : 0.f;
        const float vpp = (okp && olp) ? p[IW + 1] : 0.f;
        a00 = fmaf(v00, wp[1 * 4 + 1], a00);
        a00 = fmaf(v0m, wp[1 * 4 + 3], a00);
        a00 = fmaf(vm0, wp[3 * 4 + 1], a00);
        a00 = fmaf(vmm, wp[3 * 4 + 3], a00);
        a01 = fmaf(v0p, wp[1 * 4 + 0], a01);
        a01 = fmaf(v00, wp[1 * 4 + 2], a01);
        a01 = fmaf(vmp, wp[3 * 4 + 0], a01);
        a01 = fmaf(vm0, wp[3 * 4 + 2], a01);
        a10 = fmaf(vp0, wp[0 * 4 + 1], a10);
        a10 = fmaf(vpm, wp[0 * 4 + 3], a10);
        a10 = fmaf(v00, wp[2 * 4 + 1], a10);
        a10 = fmaf(v0m, wp[2 * 4 + 3], a10);
        a11 = fmaf(vpp, wp[0 * 4 + 0], a11);
        a11 = fmaf(vp0, wp[0 * 4 + 2], a11);
        a11 = fmaf(v0p, wp[2 * 4 + 0], a11);
        a11 = fmaf(v00, wp[2 * 4 + 2], a11);
    }

    float* __restrict__ outb = out + (size_t)b * 256 * 256;
    ((float2*)(outb + (size_t)(2 * i) * OW))[j] = make_float2(a00, a01);
    ((float2*)(outb + (size_t)(2 * i + 1) * OW))[j] = make_float2(a10, a11);
}

// VQ-GEMM (validated R9). DO NOT reorder any fmaf chain (R3).
__global__ __launch_bounds__(256) void vq_gemm(
    const float* __restrict__ h,    // (32,64,4096)
    const float* __restrict__ cb,   // (512,64) row-major (gather)
    const float* __restrict__ cbT,  // (64,512) dim-major (matmul)
    const float* __restrict__ ee,   // (512)
    float* __restrict__ q)          // (32,64,4096)
{
    __shared__ __align__(16) float As[64 * 128];
    __shared__ float xx_sh[128];
    __shared__ float pd[4 * 128];
    __shared__ int   pk[4 * 128];
    __shared__ int   bidx_sh[128];

    const int tid = threadIdx.x;
    const int tpx = tid & 63;
    const int w = __builtin_amdgcn_readfirstlane(tid >> 6);
    const int n0 = blockIdx.x * 128;
    const int b  = n0 >> 12;
    const int hw0 = n0 & 4095;

    const float* __restrict__ hb = h + (size_t)b * 64 * 4096 + hw0;
#pragma unroll
    for (int m = 0; m < 32; m++) {
        const int idx = m * 256 + tid;
        const int k = idx >> 7, p = idx & 127;
        As[idx] = hb[(size_t)k * 4096 + p];
    }
    __syncthreads();

    if (tid < 128) {
        float s = 0.0f;
#pragma unroll
        for (int i = 0; i < 64; i++) {
            const float v = As[i * 128 + tid];
            s = fmaf(v, v, s);
        }
        xx_sh[tid] = s;
    }
    __syncthreads();

    const float xx0 = xx_sh[tpx * 2];
    const float xx1 = xx_sh[tpx * 2 + 1];
    const int cwave = w * 128;

    float best0 = 3.402823466e+38f, best1 = 3.402823466e+38f;
    int bk0 = 0, bk1 = 0;

#pragma unroll 1
    for (int ch = 0; ch < 16; ch++) {
        const int cbase = cwave + ch * 8;
        float acc[8][2];
#pragma unroll
        for (int c = 0; c < 8; c++) { acc[c][0] = 0.0f; acc[c][1] = 0.0f; }

#pragma unroll 8
        for (int k = 0; k < 64; k++) {
            const float2 a2 = *(const float2*)(As + k * 128 + tpx * 2);
            const float* __restrict__ wk = cbT + (size_t)k * 512 + cbase;
#pragma unroll
            for (int c = 0; c < 8; c++) {
                const float wv = wk[c];
                acc[c][0] = fmaf(a2.x, wv, acc[c][0]);
                acc[c][1] = fmaf(a2.y, wv, acc[c][1]);
            }
        }
        const float* __restrict__ eep = ee + cbase;
#pragma unroll
        for (int c = 0; c < 8; c++) {
            const float eec = eep[c];
            const float d0 = xx0 - 2.0f * acc[c][0] + eec;
            const float d1 = xx1 - 2.0f * acc[c][1] + eec;
            if (d0 < best0) { best0 = d0; bk0 = cbase + c; }
            if (d1 < best1) { best1 = d1; bk1 = cbase + c; }
        }
    }

    pd[w * 128 + tpx * 2]     = best0;
    pd[w * 128 + tpx * 2 + 1] = best1;
    pk[w * 128 + tpx * 2]     = bk0;
    pk[w * 128 + tpx * 2 + 1] = bk1;
    __syncthreads();

    if (tid < 128) {
        float bd = pd[tid]; int bk = pk[tid];
#pragma unroll
        for (int ww = 1; ww < 4; ww++) {
            const float od = pd[ww * 128 + tid];
            if (od < bd) { bd = od; bk = pk[ww * 128 + tid]; }
        }
        bidx_sh[tid] = bk;
    }
    __syncthreads();

    {
        const int p  = tid & 127;
        const int d0 = (tid >> 7) * 32;
        const int bk = bidx_sh[p];
        const float4* __restrict__ cp4 = (const float4*)(cb + (size_t)bk * 64 + d0);
        float* __restrict__ qb = q + ((size_t)b * 64 + d0) * 4096 + hw0 + p;
#pragma unroll
        for (int i = 0; i < 8; i++) {
            const float4 v = cp4[i];
            qb[(size_t)(4 * i + 0) * 4096] = v.x;
            qb[(size_t)(4 * i + 1) * 4096] = v.y;
            qb[(size_t)(4 * i + 2) * 4096] = v.z;
            qb[(size_t)(4 * i + 3) * 4096] = v.w;
        }
    }
}

extern "C" void kernel_launch(void* const* d_in, const int* in_sizes, int n_in,
                              void* d_out, int out_size, void* d_ws, size_t ws_size,
                              hipStream_t stream) {
    const float* x      = (const float*)d_in[0];
    const float* w_e1   = (const float*)d_in[1];
    const float* b_e1   = (const float*)d_in[2];
    const float* w_e2   = (const float*)d_in[3];
    const float* b_e2   = (const float*)d_in[4];
    const float* w_er1a = (const float*)d_in[5];
    const float* w_er1b = (const float*)d_in[6];
    const float* w_er2a = (const float*)d_in[7];
    const float* w_er2b = (const float*)d_in[8];
    const float* w_pre  = (const float*)d_in[9];
    const float* b_pre  = (const float*)d_in[10];
    const float* cbk    = (const float*)d_in[11];
    const float* w_d1   = (const float*)d_in[12];
    const float* b_d1   = (const float*)d_in[13];
    const float* w_dr1a = (const float*)d_in[14];
    const float* w_dr1b = (const float*)d_in[15];
    const float* w_dr2a = (const float*)d_in[16];
    const float* w_dr2b = (const float*)d_in[17];
    const float* w_t1   = (const float*)d_in[18];
    const float* b_t1   = (const float*)d_in[19];
    const float* w_t2   = (const float*)d_in[20];
    const float* b_t2   = (const float*)d_in[21];
    float* out = (float*)d_out;

    float* A  = (float*)d_ws;            // 16777216 floats (scratch + t1 out)
    float* Bb = A  + 16777216;           // (32,64,64,64) = 8388608
    float* C  = Bb + 8388608;            // 4194304 (unused after fusion)
    float* D  = C  + 4194304;            // (32,64,64,64) = 8388608
    float* WR = D  + 8388608;            // repacked weights + cbT (221696)
    float* EE = WR + 221696;             // ee (512)

    float* r_e1  = WR;
    float* r_e2  = WR + 512;
    float* r_er1a = WR + 33280;
    float* r_er1b = WR + 51712;
    float* r_er2a = WR + 53760;
    float* r_er2b = WR + 72192;
    float* r_pre = WR + 74240;
    float* r_d1  = WR + 78336;
    float* r_dr1a = WR + 115200;
    float* r_dr1b = WR + 133632;
    float* r_dr2a = WR + 135680;
    float* r_dr2b = WR + 154112;
    float* r_t1  = WR + 156160;
    float* r_cbT = WR + 188928;

    const dim3 blk(256);

    repack_all<<<dim3(866), blk, 0, stream>>>(
        w_e1, w_e2, w_er1a, w_er1b, w_er2a, w_er2b, w_pre, w_d1,
        w_dr1a, w_dr1b, w_dr2a, w_dr2b, w_t1, cbk, WR);
    vq_prep_ee<<<dim3(2), blk, 0, stream>>>(cbk, EE);

    // Encoder
    conv_gemm<32, 32, 1, 4, 2, 1, false, true, false, true>
        <<<dim3(2048, 1), blk, 0, stream>>>(x, r_e1, b_e1, nullptr, A,
                                            256, 256, 128, 128);
    conv_gemm<64, 16, 32, 4, 2, 1, false, true, false, false>
        <<<dim3(512, 4), blk, 0, stream>>>(A, r_e2, b_e2, nullptr, Bb,
                                           128, 128, 64, 64);
    // er1: Bb -> A ; er2: A -> Bb (ping-pong avoids in-place halo race)
    res_fused<<<dim3(512), blk, 0, stream>>>(Bb, r_er1a, r_er1b, A);
    res_fused<<<dim3(512), blk, 0, stream>>>(A, r_er2a, r_er2b, Bb);
    conv_gemm<64, 16, 64, 1, 1, 0, false, true, false, false>
        <<<dim3(512, 4), blk, 0, stream>>>(Bb, r_pre, b_pre, nullptr, D,
                                           64, 64, 64, 64);
    // VQ
    vq_gemm<<<dim3(1024), blk, 0, stream>>>(D, cbk, r_cbT, EE, Bb);
    // Decoder
    conv_gemm<64, 16, 64, 3, 1, 1, false, true, false, false>
        <<<dim3(512, 4), blk, 0, stream>>>(Bb, r_d1, b_d1, nullptr, D,
                                           64, 64, 64, 64);
    // dr1: D -> A ; dr2: A -> D
    res_fused<<<dim3(512), blk, 0, stream>>>(D, r_dr1a, r_dr1b, A);
    res_fused<<<dim3(512), blk, 0, stream>>>(A, r_dr2a, r_dr2b, D);
    // t1 (pc-merged, cout-split): grid (512, 2pr x 2cg)
    convt_gemm2<<<dim3(512, 4), blk, 0, stream>>>(D, r_t1, b_t1, A);
    // t2
    convt2_quad<<<dim3(64, 32), blk, 0, stream>>>(A, w_t2, b_t2, out, 32);
}